// Round 1
// baseline (361.283 us; speedup 1.0000x reference)
//
#include <hip/hip_runtime.h>
#include <hip/hip_bf16.h>

#define B_ 4
#define NIN_ 32
#define H_ 14
#define W_ 14
#define DIN_ 8
#define NOUT_ 32
#define DOUT_ 16
#define K_ 3
#define OH_ 12
#define OW_ 12
#define PROJ_ 512
#define HID_ 128
#define M_ 288            // NIN*K*K
#define NPIX_ (B_*NIN_*H_*W_)   // 25088
#define PPB 16            // pixels per block in MLP kernel

__device__ __forceinline__ float bflo(unsigned int u) { return __uint_as_float(u << 16); }
__device__ __forceinline__ float bfhi(unsigned int u) { return __uint_as_float(u & 0xffff0000u); }

// ---------------------------------------------------------------------------
// Kernel 1: per-pixel MLP  x[pix,8] -> relu(@W1+b1)[512] -> relu(@W2+b2)[128]
//           -> (@W3+b3)[512] -> U[pix][512] (bf16)
// ---------------------------------------------------------------------------
__global__ __launch_bounds__(256) void mlp_kernel(
    const float* __restrict__ x,
    const float* __restrict__ W1, const float* __restrict__ b1,
    const float* __restrict__ W2, const float* __restrict__ b2,
    const float* __restrict__ W3, const float* __restrict__ b3,
    __hip_bfloat16* __restrict__ U)
{
    __shared__ float xin[PPB][DIN_];     // 0.5 KB
    __shared__ float h1[PPB][PROJ_];     // 32 KB
    __shared__ float h2[PPB][HID_];      // 8 KB

    const int t = threadIdx.x;
    const int pix0 = blockIdx.x * PPB;

    // load inputs: PPB*8 = 128 floats
    if (t < PPB * DIN_) {
        int p = t / DIN_, k = t % DIN_;
        xin[p][k] = x[(pix0 + p) * DIN_ + k];
    }
    __syncthreads();

    // ---- stage 1: h1 = relu(x @ W1 + b1), 16p x 512j ----
    for (int rep = 0; rep < 2; ++rep) {
        int j = rep * 256 + t;
        float acc[PPB];
        float bb = b1[j];
        #pragma unroll
        for (int p = 0; p < PPB; ++p) acc[p] = bb;
        #pragma unroll
        for (int k = 0; k < DIN_; ++k) {
            float w = W1[k * PROJ_ + j];
            #pragma unroll
            for (int p = 0; p < PPB; ++p) acc[p] += xin[p][k] * w;
        }
        #pragma unroll
        for (int p = 0; p < PPB; ++p) h1[p][j] = fmaxf(acc[p], 0.f);
    }
    __syncthreads();

    // ---- stage 2: h2 = relu(h1 @ W2 + b2), 16p x 128j ----
    {
        int j  = t & 127;
        int ph = t >> 7;           // 0/1 -> pixels [0..7] or [8..15]
        float acc[8];
        float bb = b2[j];
        #pragma unroll
        for (int p = 0; p < 8; ++p) acc[p] = bb;
        for (int k = 0; k < PROJ_; k += 4) {
            float w0 = W2[(k + 0) * HID_ + j];
            float w1 = W2[(k + 1) * HID_ + j];
            float w2 = W2[(k + 2) * HID_ + j];
            float w3 = W2[(k + 3) * HID_ + j];
            #pragma unroll
            for (int p = 0; p < 8; ++p) {
                float4 hv = *(const float4*)&h1[ph * 8 + p][k];  // LDS broadcast
                acc[p] += hv.x * w0 + hv.y * w1 + hv.z * w2 + hv.w * w3;
            }
        }
        #pragma unroll
        for (int p = 0; p < 8; ++p) h2[ph * 8 + p][j] = fmaxf(acc[p], 0.f);
    }
    __syncthreads();

    // ---- stage 3: U = h2 @ W3 + b3, 16p x 512j, store bf16 ----
    for (int jh = 0; jh < 2; ++jh) {
        int j = jh * 256 + t;
        float acc[PPB];
        float bb = b3[j];
        #pragma unroll
        for (int p = 0; p < PPB; ++p) acc[p] = bb;
        for (int k = 0; k < HID_; k += 4) {
            float w0 = W3[(k + 0) * PROJ_ + j];
            float w1 = W3[(k + 1) * PROJ_ + j];
            float w2 = W3[(k + 2) * PROJ_ + j];
            float w3 = W3[(k + 3) * PROJ_ + j];
            #pragma unroll
            for (int p = 0; p < PPB; ++p) {
                float4 hv = *(const float4*)&h2[p][k];           // LDS broadcast
                acc[p] += hv.x * w0 + hv.y * w1 + hv.z * w2 + hv.w * w3;
            }
        }
        #pragma unroll
        for (int p = 0; p < PPB; ++p)
            U[(pix0 + p) * PROJ_ + j] = __float2bfloat16(acc[p]);
    }
}

// ---------------------------------------------------------------------------
// Kernel 2: dynamic routing per output position (b,i,j).
//   preds[m][no][d] = U[pix(b,m,i,j)][no*16+d],  m = n*9 + ki*3 + kj
// ---------------------------------------------------------------------------
__global__ __launch_bounds__(256) void route_kernel(
    const __hip_bfloat16* __restrict__ Ub,
    float* __restrict__ out_v,    // (B, NOUT, OH, OW, DOUT)
    float* __restrict__ out_ent)  // (B, M, 1, OH, OW)
{
    const unsigned int* __restrict__ U32 = (const unsigned int*)Ub;

    __shared__ float bL[M_][NOUT_ + 1];   // 38,016 B
    __shared__ float cL[M_][NOUT_ + 1];   // 38,016 B
    __shared__ float sv[PROJ_];           // 2 KB   s in layout no*16+d
    __shared__ float vv[NOUT_][DOUT_ + 1];// 2.1 KB (pad 17 -> conflict-free)
    __shared__ float scaleL[NOUT_];
    __shared__ int   pixoff[M_];

    const int bid = blockIdx.x;
    const int b  = bid / (OH_ * OW_);
    const int ij = bid % (OH_ * OW_);
    const int i  = ij / OW_, j = ij % OW_;
    const int t  = threadIdx.x;

    // init logits + pixel offsets
    for (int idx = t; idx < M_ * NOUT_; idx += 256) {
        int m = idx >> 5, no = idx & 31;
        bL[m][no] = 0.f;
    }
    for (int m = t; m < M_; m += 256) {
        int n = m / 9, r = m % 9, ki = r / 3, kj = r % 3;
        pixoff[m] = ((b * NIN_ + n) * H_ + (i + ki)) * W_ + (j + kj);
    }
    __syncthreads();

    for (int it = 0; it < 3; ++it) {
        // ---- softmax over NOUT per m-row -> cL ----
        for (int m = t; m < M_; m += 256) {
            float mx = -1e30f;
            #pragma unroll
            for (int no = 0; no < NOUT_; ++no) mx = fmaxf(mx, bL[m][no]);
            float ssum = 0.f;
            #pragma unroll
            for (int no = 0; no < NOUT_; ++no) {
                float e = __expf(bL[m][no] - mx);
                cL[m][no] = e;
                ssum += e;
            }
            float inv = 1.f / ssum;
            #pragma unroll
            for (int no = 0; no < NOUT_; ++no) cL[m][no] *= inv;
        }
        __syncthreads();

        // ---- s[no,d] = sum_m c[m,no] * preds[m,no,d] ----
        {
            const int no = t >> 3;            // t = no*8 + dpair
            float acc0 = 0.f, acc1 = 0.f;
            #pragma unroll 4
            for (int m = 0; m < M_; ++m) {
                int pix = pixoff[m];                       // LDS broadcast
                float c = cL[m][no];
                unsigned int u = U32[pix * 256 + t];       // 2 bf16, coalesced
                acc0 += c * bflo(u);
                acc1 += c * bfhi(u);
            }
            sv[2 * t]     = acc0;
            sv[2 * t + 1] = acc1;
        }
        __syncthreads();

        // ---- squash scale per capsule ----
        if (t < NOUT_) {
            float ns = 0.f;
            #pragma unroll
            for (int d = 0; d < DOUT_; ++d) { float s = sv[t * 16 + d]; ns += s * s; }
            scaleL[t] = ns / (1.f + ns) * rsqrtf(ns + 1e-16f);
        }
        __syncthreads();
        {
            int no = t >> 3, dp = t & 7;
            float sc = scaleL[no];
            vv[no][2 * dp]     = sv[2 * t] * sc;
            vv[no][2 * dp + 1] = sv[2 * t + 1] * sc;
        }
        __syncthreads();

        if (it < 2) {
            // ---- b[m,no] += dot(preds[m,no,:], v[no,:]) ----
            for (int flat = t; flat < M_ * NOUT_; flat += 256) {
                int m = flat >> 5, no = flat & 31;
                int pix = pixoff[m];
                const uint4* up4 = (const uint4*)(U32 + pix * 256 + no * 8);
                unsigned int us[8];
                *(uint4*)&us[0] = up4[0];
                *(uint4*)&us[4] = up4[1];
                float dot = 0.f;
                #pragma unroll
                for (int q = 0; q < 8; ++q) {
                    dot += bflo(us[q]) * vv[no][2 * q]
                         + bfhi(us[q]) * vv[no][2 * q + 1];
                }
                bL[m][no] += dot;
            }
            __syncthreads();
        } else {
            // ---- final outputs ----
            {   // v output: vv[no][d] -> out_v[((b*32+no)*12+i)*12+j][d]
                int no = t >> 3, dp = t & 7;
                int o = (((b * NOUT_ + no) * OH_ + i) * OW_ + j) * DOUT_ + 2 * dp;
                out_v[o]     = vv[no][2 * dp];
                out_v[o + 1] = vv[no][2 * dp + 1];
            }
            // entropy per m-row from final c
            for (int m = t; m < M_; m += 256) {
                float ent = 0.f;
                #pragma unroll
                for (int no = 0; no < NOUT_; ++no) {
                    float c = cL[m][no];
                    ent -= c * __logf(c + 1e-16f);
                }
                out_ent[(b * M_ + m) * (OH_ * OW_) + i * OW_ + j] =
                    ent * 0.28853900817779268f;  // 1/log(32)
            }
        }
    }
}

extern "C" void kernel_launch(void* const* d_in, const int* in_sizes, int n_in,
                              void* d_out, int out_size, void* d_ws, size_t ws_size,
                              hipStream_t stream) {
    const float* x  = (const float*)d_in[0];
    const float* W1 = (const float*)d_in[1];
    const float* b1 = (const float*)d_in[2];
    const float* W2 = (const float*)d_in[3];
    const float* b2 = (const float*)d_in[4];
    const float* W3 = (const float*)d_in[5];
    const float* b3 = (const float*)d_in[6];

    __hip_bfloat16* U = (__hip_bfloat16*)d_ws;   // NPIX_*512*2 = 24.5 MB
    float* out_v   = (float*)d_out;
    float* out_ent = out_v + (size_t)B_ * NOUT_ * OH_ * OW_ * DOUT_;

    hipLaunchKernelGGL(mlp_kernel, dim3(NPIX_ / PPB), dim3(256), 0, stream,
                       x, W1, b1, W2, b2, W3, b3, U);
    hipLaunchKernelGGL(route_kernel, dim3(B_ * OH_ * OW_), dim3(256), 0, stream,
                       U, out_v, out_ent);
}

// Round 2
// 237.944 us; speedup vs baseline: 1.5184x; 1.5184x over previous
//
#include <hip/hip_runtime.h>
#include <hip/hip_bf16.h>

#define B_ 4
#define NIN_ 32
#define H_ 14
#define W_ 14
#define DIN_ 8
#define NOUT_ 32
#define DOUT_ 16
#define K_ 3
#define OH_ 12
#define OW_ 12
#define PROJ_ 512
#define HID_ 128
#define M_ 288                  // NIN*K*K
#define NPIX_ (B_*NIN_*H_*W_)   // 25088

typedef __attribute__((ext_vector_type(8))) short short8;
typedef __attribute__((ext_vector_type(4))) float f32x4;

__device__ __forceinline__ float bflo(unsigned int u) { return __uint_as_float(u << 16); }
__device__ __forceinline__ float bfhi(unsigned int u) { return __uint_as_float(u & 0xffff0000u); }
__device__ __forceinline__ unsigned short bfbits(float f) {
    __hip_bfloat16 h = __float2bfloat16(f);
    return *(unsigned short*)&h;
}

// ---------------------------------------------------------------------------
// Prep: convert W2 (512x128 f32) and W3 (128x512 f32) to bf16 in MFMA
// B-fragment order.  Frag (nt,kt): lane l holds W[kt*32+(l>>4)*8+j][nt*16+(l&15)].
// W2B: [nt(8)][kt(16)][lane(64)][j(8)]   W3B: [nt(32)][kt(4)][lane(64)][j(8)]
// ---------------------------------------------------------------------------
__global__ __launch_bounds__(256) void prep_kernel(
    const float* __restrict__ W2, const float* __restrict__ W3,
    __hip_bfloat16* __restrict__ W2B, __hip_bfloat16* __restrict__ W3B)
{
    int idx = blockIdx.x * 256 + threadIdx.x;  // [0, 65536)
    {
        int j = idx & 7, lane = (idx >> 3) & 63, kt = (idx >> 9) & 15, nt = idx >> 13;
        int k = kt * 32 + (lane >> 4) * 8 + j;
        int c = nt * 16 + (lane & 15);
        W2B[idx] = __float2bfloat16(W2[k * HID_ + c]);
    }
    {
        int j = idx & 7, lane = (idx >> 3) & 63, kt = (idx >> 9) & 3, nt = idx >> 11;
        int k = kt * 32 + (lane >> 4) * 8 + j;
        int c = nt * 16 + (lane & 15);
        W3B[idx] = __float2bfloat16(W3[k * PROJ_ + c]);
    }
}

// ---------------------------------------------------------------------------
// Fused MLP, 64 pixels/block, 4 waves.
//   stage1 (vector f32): h1 = relu(x@W1+b1) -> LDS bf16 in A-frag layout
//   stage2 (MFMA):       h2 = relu(h1@W2+b2) -> LDS bf16 A-frag layout
//   stage3 (MFMA):       U  = h2@W3+b3 -> global bf16 [pix][512]
// A-frag layout for (p,k): flat = ((mt*KT+kt)*64 + ((k>>3)&3)*16 + (p&15))*8 + (k&7)
//   with mt=p>>4, kt=k>>5.
// ---------------------------------------------------------------------------
__global__ __launch_bounds__(256) void mlp_mfma_kernel(
    const float* __restrict__ x,
    const float* __restrict__ W1, const float* __restrict__ b1,
    const short8* __restrict__ W2B, const float* __restrict__ b2,
    const short8* __restrict__ W3B, const float* __restrict__ b3,
    __hip_bfloat16* __restrict__ U)
{
    // 67.5 KB total -> 2 blocks/CU.  h2A overlays h1A after a barrier.
    __shared__ short smem[33792];
    short* h1A = smem;                                  // 32768 shorts (64 KB)
    float (*xin)[8] = (float(*)[8])(smem + 32768);      // 512 floats (2 KB)

    const int t = threadIdx.x;
    const int pix0 = blockIdx.x * 64;
    const int l = t & 63, wv = t >> 6;                  // lane, wave(=m-tile)

    // ---- load x tile ----
    {
        int idx = t;
        #pragma unroll
        for (int rep = 0; rep < 2; ++rep, idx += 256) {
            int p = idx >> 3, c = idx & 7;
            xin[p][c] = x[(pix0 + p) * DIN_ + c];
        }
    }

    // ---- stage 1: thread owns columns k0=2t, k0+1; loops all 64 pixels ----
    {
        const int k0 = 2 * t;
        float w0[8], w1[8];
        #pragma unroll
        for (int c = 0; c < 8; ++c) {
            w0[c] = W1[c * PROJ_ + k0];
            w1[c] = W1[c * PROJ_ + k0 + 1];
        }
        const float bb0 = b1[k0], bb1 = b1[k0 + 1];
        const int kt = k0 >> 5, hi = (k0 >> 3) & 3, j = k0 & 7;
        const int base_k = (kt * 64 + hi * 16) * 8 + j;   // add mt*8192 + r*8
        unsigned int* h1w = (unsigned int*)h1A;
        __syncthreads();                                  // xin ready
        for (int p = 0; p < 64; ++p) {
            float4 xa = *(const float4*)&xin[p][0];       // LDS broadcast
            float4 xb = *(const float4*)&xin[p][4];
            float a0 = bb0 + xa.x*w0[0] + xa.y*w0[1] + xa.z*w0[2] + xa.w*w0[3]
                           + xb.x*w0[4] + xb.y*w0[5] + xb.z*w0[6] + xb.w*w0[7];
            float a1 = bb1 + xa.x*w1[0] + xa.y*w1[1] + xa.z*w1[2] + xa.w*w1[3]
                           + xb.x*w1[4] + xb.y*w1[5] + xb.z*w1[6] + xb.w*w1[7];
            a0 = fmaxf(a0, 0.f); a1 = fmaxf(a1, 0.f);
            unsigned int packed = (unsigned int)bfbits(a0)
                                | ((unsigned int)bfbits(a1) << 16);
            int flat = (p >> 4) * 8192 + base_k + (p & 15) * 8;  // j even -> u32 ok
            h1w[flat >> 1] = packed;
        }
    }
    __syncthreads();

    // ---- stage 2: h2[64][128] = relu(h1 @ W2 + b2), MFMA ----
    f32x4 acc2[8];
    {
        const short8* h1f = (const short8*)h1A;
        #pragma unroll
        for (int nt = 0; nt < 8; ++nt) acc2[nt] = (f32x4){0.f, 0.f, 0.f, 0.f};
        for (int ktk = 0; ktk < 16; ++ktk) {
            short8 a = h1f[(wv * 16 + ktk) * 64 + l];
            #pragma unroll
            for (int nt = 0; nt < 8; ++nt) {
                short8 b = W2B[(nt * 16 + ktk) * 64 + l];
                acc2[nt] = __builtin_amdgcn_mfma_f32_16x16x32_bf16(a, b, acc2[nt], 0, 0, 0);
            }
        }
    }
    __syncthreads();                  // all h1A reads done; safe to overlay h2A
    short* h2A = smem;
    {
        const int r0 = (l >> 4) * 4;
        #pragma unroll
        for (int nt = 0; nt < 8; ++nt) {
            int c = nt * 16 + (l & 15);
            float bb = b2[c];
            int kt3 = c >> 5;
            int lane3base = ((c >> 3) & 3) * 16;
            #pragma unroll
            for (int q = 0; q < 4; ++q) {
                float v = fmaxf(acc2[nt][q] + bb, 0.f);
                int flat = ((wv * 4 + kt3) * 64 + lane3base + r0 + q) * 8 + (c & 7);
                h2A[flat] = (short)bfbits(v);
            }
        }
    }
    __syncthreads();

    // ---- stage 3: U[64][512] = h2 @ W3 + b3, MFMA ----
    {
        const short8* h2f = (const short8*)h2A;
        short8 a[4];
        #pragma unroll
        for (int ktk = 0; ktk < 4; ++ktk) a[ktk] = h2f[(wv * 4 + ktk) * 64 + l];
        const int r0 = (l >> 4) * 4;
        for (int pass = 0; pass < 4; ++pass) {
            f32x4 acc[8];
            #pragma unroll
            for (int nt2 = 0; nt2 < 8; ++nt2) acc[nt2] = (f32x4){0.f, 0.f, 0.f, 0.f};
            #pragma unroll
            for (int nt2 = 0; nt2 < 8; ++nt2) {
                int nt = pass * 8 + nt2;
                #pragma unroll
                for (int ktk = 0; ktk < 4; ++ktk) {
                    short8 b = W3B[(nt * 4 + ktk) * 64 + l];
                    acc[nt2] = __builtin_amdgcn_mfma_f32_16x16x32_bf16(a[ktk], b, acc[nt2], 0, 0, 0);
                }
            }
            #pragma unroll
            for (int nt2 = 0; nt2 < 8; ++nt2) {
                int c = (pass * 8 + nt2) * 16 + (l & 15);
                float bb = b3[c];
                #pragma unroll
                for (int q = 0; q < 4; ++q) {
                    U[(size_t)(pix0 + wv * 16 + r0 + q) * PROJ_ + c] =
                        __float2bfloat16(acc[nt2][q] + bb);
                }
            }
        }
    }
}

// ---------------------------------------------------------------------------
// Kernel 2: dynamic routing per output position (b,i,j).  (unchanged)
//   preds[m][no][d] = U[pix(b,m,i,j)][no*16+d],  m = n*9 + ki*3 + kj
// ---------------------------------------------------------------------------
__global__ __launch_bounds__(256) void route_kernel(
    const __hip_bfloat16* __restrict__ Ub,
    float* __restrict__ out_v,    // (B, NOUT, OH, OW, DOUT)
    float* __restrict__ out_ent)  // (B, M, 1, OH, OW)
{
    const unsigned int* __restrict__ U32 = (const unsigned int*)Ub;

    __shared__ float bL[M_][NOUT_ + 1];
    __shared__ float cL[M_][NOUT_ + 1];
    __shared__ float sv[PROJ_];
    __shared__ float vv[NOUT_][DOUT_ + 1];
    __shared__ float scaleL[NOUT_];
    __shared__ int   pixoff[M_];

    const int bid = blockIdx.x;
    const int b  = bid / (OH_ * OW_);
    const int ij = bid % (OH_ * OW_);
    const int i  = ij / OW_, j = ij % OW_;
    const int t  = threadIdx.x;

    for (int idx = t; idx < M_ * NOUT_; idx += 256) {
        int m = idx >> 5, no = idx & 31;
        bL[m][no] = 0.f;
    }
    for (int m = t; m < M_; m += 256) {
        int n = m / 9, r = m % 9, ki = r / 3, kj = r % 3;
        pixoff[m] = ((b * NIN_ + n) * H_ + (i + ki)) * W_ + (j + kj);
    }
    __syncthreads();

    for (int it = 0; it < 3; ++it) {
        // softmax over NOUT per m-row -> cL
        for (int m = t; m < M_; m += 256) {
            float mx = -1e30f;
            #pragma unroll
            for (int no = 0; no < NOUT_; ++no) mx = fmaxf(mx, bL[m][no]);
            float ssum = 0.f;
            #pragma unroll
            for (int no = 0; no < NOUT_; ++no) {
                float e = __expf(bL[m][no] - mx);
                cL[m][no] = e;
                ssum += e;
            }
            float inv = 1.f / ssum;
            #pragma unroll
            for (int no = 0; no < NOUT_; ++no) cL[m][no] *= inv;
        }
        __syncthreads();

        // s[no,d] = sum_m c[m,no] * preds[m,no,d]
        {
            const int no = t >> 3;
            float acc0 = 0.f, acc1 = 0.f;
            #pragma unroll 4
            for (int m = 0; m < M_; ++m) {
                int pix = pixoff[m];
                float c = cL[m][no];
                unsigned int u = U32[pix * 256 + t];
                acc0 += c * bflo(u);
                acc1 += c * bfhi(u);
            }
            sv[2 * t]     = acc0;
            sv[2 * t + 1] = acc1;
        }
        __syncthreads();

        if (t < NOUT_) {
            float ns = 0.f;
            #pragma unroll
            for (int d = 0; d < DOUT_; ++d) { float s = sv[t * 16 + d]; ns += s * s; }
            scaleL[t] = ns / (1.f + ns) * rsqrtf(ns + 1e-16f);
        }
        __syncthreads();
        {
            int no = t >> 3, dp = t & 7;
            float sc = scaleL[no];
            vv[no][2 * dp]     = sv[2 * t] * sc;
            vv[no][2 * dp + 1] = sv[2 * t + 1] * sc;
        }
        __syncthreads();

        if (it < 2) {
            for (int flat = t; flat < M_ * NOUT_; flat += 256) {
                int m = flat >> 5, no = flat & 31;
                int pix = pixoff[m];
                const uint4* up4 = (const uint4*)(U32 + pix * 256 + no * 8);
                unsigned int us[8];
                *(uint4*)&us[0] = up4[0];
                *(uint4*)&us[4] = up4[1];
                float dot = 0.f;
                #pragma unroll
                for (int q = 0; q < 8; ++q) {
                    dot += bflo(us[q]) * vv[no][2 * q]
                         + bfhi(us[q]) * vv[no][2 * q + 1];
                }
                bL[m][no] += dot;
            }
            __syncthreads();
        } else {
            {
                int no = t >> 3, dp = t & 7;
                int o = (((b * NOUT_ + no) * OH_ + i) * OW_ + j) * DOUT_ + 2 * dp;
                out_v[o]     = vv[no][2 * dp];
                out_v[o + 1] = vv[no][2 * dp + 1];
            }
            for (int m = t; m < M_; m += 256) {
                float ent = 0.f;
                #pragma unroll
                for (int no = 0; no < NOUT_; ++no) {
                    float c = cL[m][no];
                    ent -= c * __logf(c + 1e-16f);
                }
                out_ent[(b * M_ + m) * (OH_ * OW_) + i * OW_ + j] =
                    ent * 0.28853900817779268f;  // 1/log(32)
            }
        }
    }
}

extern "C" void kernel_launch(void* const* d_in, const int* in_sizes, int n_in,
                              void* d_out, int out_size, void* d_ws, size_t ws_size,
                              hipStream_t stream) {
    const float* x  = (const float*)d_in[0];
    const float* W1 = (const float*)d_in[1];
    const float* b1 = (const float*)d_in[2];
    const float* W2 = (const float*)d_in[3];
    const float* b2 = (const float*)d_in[4];
    const float* W3 = (const float*)d_in[5];
    const float* b3 = (const float*)d_in[6];

    // ws layout: U (25,690,112 B) | W2B (131,072 B) | W3B (131,072 B)
    char* ws = (char*)d_ws;
    __hip_bfloat16* U   = (__hip_bfloat16*)ws;
    __hip_bfloat16* W2B = (__hip_bfloat16*)(ws + (size_t)NPIX_ * PROJ_ * 2);
    __hip_bfloat16* W3B = W2B + (size_t)PROJ_ * HID_;

    float* out_v   = (float*)d_out;
    float* out_ent = out_v + (size_t)B_ * NOUT_ * OH_ * OW_ * DOUT_;

    hipLaunchKernelGGL(prep_kernel, dim3(256), dim3(256), 0, stream,
                       W2, W3, W2B, W3B);
    hipLaunchKernelGGL(mlp_mfma_kernel, dim3(NPIX_ / 64), dim3(256), 0, stream,
                       x, W1, b1, (const short8*)W2B, b2, (const short8*)W3B, b3, U);
    hipLaunchKernelGGL(route_kernel, dim3(B_ * OH_ * OW_), dim3(256), 0, stream,
                       U, out_v, out_ent);
}

// Round 3
// 147.400 us; speedup vs baseline: 2.4510x; 1.6143x over previous
//
#include <hip/hip_runtime.h>
#include <hip/hip_bf16.h>

#define B_ 4
#define NIN_ 32
#define H_ 14
#define W_ 14
#define DIN_ 8
#define NOUT_ 32
#define DOUT_ 16
#define K_ 3
#define OH_ 12
#define OW_ 12
#define PROJ_ 512
#define HID_ 128
#define M_ 288                  // NIN*K*K
#define NPIX_ (B_*NIN_*H_*W_)   // 25088

typedef __attribute__((ext_vector_type(8))) short short8;
typedef __attribute__((ext_vector_type(4))) float f32x4;

__device__ __forceinline__ float bflo(unsigned int u) { return __uint_as_float(u << 16); }
__device__ __forceinline__ float bfhi(unsigned int u) { return __uint_as_float(u & 0xffff0000u); }
__device__ __forceinline__ unsigned short bfbits(float f) {
    __hip_bfloat16 h = __float2bfloat16(f);
    return *(unsigned short*)&h;
}

// ---------------------------------------------------------------------------
// Prep: W2 (512x128) and W3 (128x512) f32 -> bf16 in MFMA B-fragment order.
// ---------------------------------------------------------------------------
__global__ __launch_bounds__(256) void prep_kernel(
    const float* __restrict__ W2, const float* __restrict__ W3,
    __hip_bfloat16* __restrict__ W2B, __hip_bfloat16* __restrict__ W3B)
{
    int idx = blockIdx.x * 256 + threadIdx.x;  // [0, 65536)
    {
        int j = idx & 7, lane = (idx >> 3) & 63, kt = (idx >> 9) & 15, nt = idx >> 13;
        int k = kt * 32 + (lane >> 4) * 8 + j;
        int c = nt * 16 + (lane & 15);
        W2B[idx] = __float2bfloat16(W2[k * HID_ + c]);
    }
    {
        int j = idx & 7, lane = (idx >> 3) & 63, kt = (idx >> 9) & 3, nt = idx >> 11;
        int k = kt * 32 + (lane >> 4) * 8 + j;
        int c = nt * 16 + (lane & 15);
        W3B[idx] = __float2bfloat16(W3[k * PROJ_ + c]);
    }
}

// ---------------------------------------------------------------------------
// Fused MLP, 64 pixels/block, 4 waves (unchanged from round 2).
// ---------------------------------------------------------------------------
__global__ __launch_bounds__(256) void mlp_mfma_kernel(
    const float* __restrict__ x,
    const float* __restrict__ W1, const float* __restrict__ b1,
    const short8* __restrict__ W2B, const float* __restrict__ b2,
    const short8* __restrict__ W3B, const float* __restrict__ b3,
    __hip_bfloat16* __restrict__ U)
{
    __shared__ short smem[33792];
    short* h1A = smem;
    float (*xin)[8] = (float(*)[8])(smem + 32768);

    const int t = threadIdx.x;
    const int pix0 = blockIdx.x * 64;
    const int l = t & 63, wv = t >> 6;

    {
        int idx = t;
        #pragma unroll
        for (int rep = 0; rep < 2; ++rep, idx += 256) {
            int p = idx >> 3, c = idx & 7;
            xin[p][c] = x[(pix0 + p) * DIN_ + c];
        }
    }

    {
        const int k0 = 2 * t;
        float w0[8], w1[8];
        #pragma unroll
        for (int c = 0; c < 8; ++c) {
            w0[c] = W1[c * PROJ_ + k0];
            w1[c] = W1[c * PROJ_ + k0 + 1];
        }
        const float bb0 = b1[k0], bb1 = b1[k0 + 1];
        const int kt = k0 >> 5, hi = (k0 >> 3) & 3, j = k0 & 7;
        const int base_k = (kt * 64 + hi * 16) * 8 + j;
        unsigned int* h1w = (unsigned int*)h1A;
        __syncthreads();
        for (int p = 0; p < 64; ++p) {
            float4 xa = *(const float4*)&xin[p][0];
            float4 xb = *(const float4*)&xin[p][4];
            float a0 = bb0 + xa.x*w0[0] + xa.y*w0[1] + xa.z*w0[2] + xa.w*w0[3]
                           + xb.x*w0[4] + xb.y*w0[5] + xb.z*w0[6] + xb.w*w0[7];
            float a1 = bb1 + xa.x*w1[0] + xa.y*w1[1] + xa.z*w1[2] + xa.w*w1[3]
                           + xb.x*w1[4] + xb.y*w1[5] + xb.z*w1[6] + xb.w*w1[7];
            a0 = fmaxf(a0, 0.f); a1 = fmaxf(a1, 0.f);
            unsigned int packed = (unsigned int)bfbits(a0)
                                | ((unsigned int)bfbits(a1) << 16);
            int flat = (p >> 4) * 8192 + base_k + (p & 15) * 8;
            h1w[flat >> 1] = packed;
        }
    }
    __syncthreads();

    f32x4 acc2[8];
    {
        const short8* h1f = (const short8*)h1A;
        #pragma unroll
        for (int nt = 0; nt < 8; ++nt) acc2[nt] = (f32x4){0.f, 0.f, 0.f, 0.f};
        for (int ktk = 0; ktk < 16; ++ktk) {
            short8 a = h1f[(wv * 16 + ktk) * 64 + l];
            #pragma unroll
            for (int nt = 0; nt < 8; ++nt) {
                short8 b = W2B[(nt * 16 + ktk) * 64 + l];
                acc2[nt] = __builtin_amdgcn_mfma_f32_16x16x32_bf16(a, b, acc2[nt], 0, 0, 0);
            }
        }
    }
    __syncthreads();
    short* h2A = smem;
    {
        const int r0 = (l >> 4) * 4;
        #pragma unroll
        for (int nt = 0; nt < 8; ++nt) {
            int c = nt * 16 + (l & 15);
            float bb = b2[c];
            int kt3 = c >> 5;
            int lane3base = ((c >> 3) & 3) * 16;
            #pragma unroll
            for (int q = 0; q < 4; ++q) {
                float v = fmaxf(acc2[nt][q] + bb, 0.f);
                int flat = ((wv * 4 + kt3) * 64 + lane3base + r0 + q) * 8 + (c & 7);
                h2A[flat] = (short)bfbits(v);
            }
        }
    }
    __syncthreads();

    {
        const short8* h2f = (const short8*)h2A;
        short8 a[4];
        #pragma unroll
        for (int ktk = 0; ktk < 4; ++ktk) a[ktk] = h2f[(wv * 4 + ktk) * 64 + l];
        const int r0 = (l >> 4) * 4;
        for (int pass = 0; pass < 4; ++pass) {
            f32x4 acc[8];
            #pragma unroll
            for (int nt2 = 0; nt2 < 8; ++nt2) acc[nt2] = (f32x4){0.f, 0.f, 0.f, 0.f};
            #pragma unroll
            for (int nt2 = 0; nt2 < 8; ++nt2) {
                int nt = pass * 8 + nt2;
                #pragma unroll
                for (int ktk = 0; ktk < 4; ++ktk) {
                    short8 b = W3B[(nt * 4 + ktk) * 64 + l];
                    acc[nt2] = __builtin_amdgcn_mfma_f32_16x16x32_bf16(a[ktk], b, acc[nt2], 0, 0, 0);
                }
            }
            #pragma unroll
            for (int nt2 = 0; nt2 < 8; ++nt2) {
                int c = (pass * 8 + nt2) * 16 + (l & 15);
                float bb = b3[c];
                #pragma unroll
                for (int q = 0; q < 4; ++q) {
                    U[(size_t)(pix0 + wv * 16 + r0 + q) * PROJ_ + c] =
                        __float2bfloat16(acc[nt2][q] + bb);
                }
            }
        }
    }
}

// ---------------------------------------------------------------------------
// Routing, 3-pass b-linearity form.  b_it2 = preds.(v0+v1), so logits are
// recomputed on the fly: c = softmax_no(preds[m].vsum), one fused sweep per
// iteration.  512 threads = 8 waves x 36 m-rows; lane=(no,dhalf) holds 8
// d-components in registers.
// ---------------------------------------------------------------------------
__global__ __launch_bounds__(512) void route_kernel(
    const __hip_bfloat16* __restrict__ Ub,
    float* __restrict__ out_v,    // (B, NOUT, OH, OW, DOUT)
    float* __restrict__ out_ent)  // (B, M, 1, OH, OW)
{
    const uint4* __restrict__ U4 = (const uint4*)Ub;

    __shared__ int   pixoff[M_];
    __shared__ float sred[8][512];   // 16 KB
    __shared__ float sbuf[512];
    __shared__ float scl[NOUT_];
    __shared__ float vv[512];

    // XCD-clustered mapping: xcd = bid&7 (dispatch round-robin), 2 XCDs per b.
    const int bid = blockIdx.x;
    const int xcd = bid & 7, sub = bid >> 3;          // 576 = 8 * 72
    const int b  = xcd >> 1;
    const int ij = (xcd & 1) * 72 + sub;
    const int i  = ij / OW_, j = ij % OW_;
    const int t  = threadIdx.x;
    const int l  = t & 63, wv = t >> 6;
    const int no = l & 31, dh = l >> 5;

    if (t < M_) {
        int n = t / 9, r = t % 9, ki = r / 3, kj = r % 3;
        pixoff[t] = ((b * NIN_ + n) * H_ + (i + ki)) * W_ + (j + kj);
    }
    __syncthreads();

    float vr[8];                       // v0, then vsum = v0+v1
    #pragma unroll
    for (int k = 0; k < 8; ++k) vr[k] = 0.f;

    for (int pass = 0; pass < 3; ++pass) {
        float s_acc[8] = {0,0,0,0,0,0,0,0};

        int m0 = wv * 36;
        uint4 us = U4[(size_t)pixoff[m0] * 64 + no * 2 + dh];
        for (int r = 0; r < 36; ++r) {
            uint4 nxt;
            if (r + 1 < 36) nxt = U4[(size_t)pixoff[m0 + r + 1] * 64 + no * 2 + dh];
            float pv[8] = { bflo(us.x), bfhi(us.x), bflo(us.y), bfhi(us.y),
                            bflo(us.z), bfhi(us.z), bflo(us.w), bfhi(us.w) };
            if (pass == 0) {
                #pragma unroll
                for (int k = 0; k < 8; ++k) s_acc[k] += pv[k];
            } else {
                float dp = 0.f;
                #pragma unroll
                for (int k = 0; k < 8; ++k) dp += pv[k] * vr[k];
                dp += __shfl_xor(dp, 32);
                float mx = dp;
                #pragma unroll
                for (int msk = 16; msk >= 1; msk >>= 1)
                    mx = fmaxf(mx, __shfl_xor(mx, msk));
                float e = __expf(dp - mx);
                float ssum = e;
                #pragma unroll
                for (int msk = 16; msk >= 1; msk >>= 1)
                    ssum += __shfl_xor(ssum, msk);
                float c = e / ssum;
                #pragma unroll
                for (int k = 0; k < 8; ++k) s_acc[k] += c * pv[k];
                if (pass == 2) {
                    float et = -c * __logf(c + 1e-16f);
                    #pragma unroll
                    for (int msk = 16; msk >= 1; msk >>= 1)
                        et += __shfl_xor(et, msk);
                    if (l == 0)
                        out_ent[(b * M_ + (m0 + r)) * (OH_ * OW_) + ij] =
                            et * 0.28853900817779268f;  // 1/log(32)
                }
            }
            us = nxt;
        }

        // cross-wave s reduction
        #pragma unroll
        for (int k = 0; k < 8; ++k) sred[wv][no * 16 + dh * 8 + k] = s_acc[k];
        __syncthreads();
        {
            float ssm = 0.f;
            #pragma unroll
            for (int w2 = 0; w2 < 8; ++w2) ssm += sred[w2][t];
            if (pass == 0) ssm *= (1.f / 32.f);
            sbuf[t] = ssm;
        }
        __syncthreads();
        if (t < NOUT_) {
            float ns = 0.f;
            #pragma unroll
            for (int d = 0; d < DOUT_; ++d) { float s = sbuf[t * 16 + d]; ns += s * s; }
            scl[t] = ns / (1.f + ns) * rsqrtf(ns + 1e-16f);
        }
        __syncthreads();
        vv[t] = sbuf[t] * scl[t >> 4];
        __syncthreads();

        if (pass < 2) {
            #pragma unroll
            for (int k = 0; k < 8; ++k)
                vr[k] += vv[no * 16 + dh * 8 + k];   // v0, then v0+v1
        }
    }

    // final v output (vv holds v2)
    {
        int no2 = t >> 4, d = t & 15;
        out_v[(((b * NOUT_ + no2) * OH_ + i) * OW_ + j) * DOUT_ + d] = vv[t];
    }
}

extern "C" void kernel_launch(void* const* d_in, const int* in_sizes, int n_in,
                              void* d_out, int out_size, void* d_ws, size_t ws_size,
                              hipStream_t stream) {
    const float* x  = (const float*)d_in[0];
    const float* W1 = (const float*)d_in[1];
    const float* b1 = (const float*)d_in[2];
    const float* W2 = (const float*)d_in[3];
    const float* b2 = (const float*)d_in[4];
    const float* W3 = (const float*)d_in[5];
    const float* b3 = (const float*)d_in[6];

    char* ws = (char*)d_ws;
    __hip_bfloat16* U   = (__hip_bfloat16*)ws;
    __hip_bfloat16* W2B = (__hip_bfloat16*)(ws + (size_t)NPIX_ * PROJ_ * 2);
    __hip_bfloat16* W3B = W2B + (size_t)PROJ_ * HID_;

    float* out_v   = (float*)d_out;
    float* out_ent = out_v + (size_t)B_ * NOUT_ * OH_ * OW_ * DOUT_;

    hipLaunchKernelGGL(prep_kernel, dim3(256), dim3(256), 0, stream,
                       W2, W3, W2B, W3B);
    hipLaunchKernelGGL(mlp_mfma_kernel, dim3(NPIX_ / 64), dim3(256), 0, stream,
                       x, W1, b1, (const short8*)W2B, b2, (const short8*)W3B, b3, U);
    hipLaunchKernelGGL(route_kernel, dim3(B_ * OH_ * OW_), dim3(512), 0, stream,
                       U, out_v, out_ent);
}